// Round 11
// baseline (409.808 us; speedup 1.0000x reference)
//
#include <hip/hip_runtime.h>
#include <hip/hip_bf16.h>
#include <cmath>

typedef __bf16 bf16;
typedef bf16 bf16x4 __attribute__((ext_vector_type(4)));
typedef bf16 bf16x8 __attribute__((ext_vector_type(8)));
typedef float f32x4 __attribute__((ext_vector_type(4)));

constexpr int H = 16, DIN = 1024, D = 64, NB = 2, S = 2048;
constexpr int BS = NB * S;  // 4096 rows
constexpr float LOG2E = 1.4426950408889634f;

// exp2: lowers to a single v_exp_f32 (HW exp is base-2)
__device__ __forceinline__ float exp2_hw(float x) {
#if __has_builtin(__builtin_amdgcn_exp2f)
    return __builtin_amdgcn_exp2f(x);
#else
    return exp2f(x);
#endif
}

// async global->LDS, 16B per lane; dest = wave-uniform base + lane*16
__device__ __forceinline__ void gld16(const bf16* g, bf16* lbase, int lane) {
#if __has_builtin(__builtin_amdgcn_global_load_lds)
    __builtin_amdgcn_global_load_lds((const __attribute__((address_space(1))) unsigned int*)g,
                                     (__attribute__((address_space(3))) unsigned int*)lbase,
                                     16, 0, 0);
#else
    *(float4*)((char*)lbase + lane * 16) = *(const float4*)g;
#endif
}

// ---------------- fp32 -> bf16 elementwise convert, 3 tensors in one dispatch ----------------
__global__ __launch_bounds__(256) void cvt3_f32_bf16(const float4* __restrict__ in0,
                                                     const float4* __restrict__ in1,
                                                     const float4* __restrict__ in2,
                                                     bf16x4* __restrict__ out0,
                                                     bf16x4* __restrict__ out1,
                                                     bf16x4* __restrict__ out2, int n4) {
    int i = blockIdx.x * 256 + threadIdx.x;
    if (i >= n4) return;
    const float4* in = blockIdx.y == 0 ? in0 : (blockIdx.y == 1 ? in1 : in2);
    bf16x4* out = blockIdx.y == 0 ? out0 : (blockIdx.y == 1 ? out1 : out2);
    float4 v = in[i];
    bf16x4 o = {(bf16)v.x, (bf16)v.y, (bf16)v.z, (bf16)v.w};
    out[i] = o;
}

// ---------------- transpose + convert: per-head Wq/Wk/Wv [DIN][64] -> [64][DIN] ----------------
__global__ __launch_bounds__(256) void transpose3_cvt(const float* __restrict__ w0,
                                                      const float* __restrict__ w1,
                                                      const float* __restrict__ w2,
                                                      bf16* __restrict__ o0,
                                                      bf16* __restrict__ o1,
                                                      bf16* __restrict__ o2) {
    __shared__ float t[32][33];
    int z = blockIdx.z, which = z / H, h = z % H;
    const float* src = (which == 0 ? w0 : (which == 1 ? w1 : w2)) + (long)h * DIN * D;
    bf16* dst = (which == 0 ? o0 : (which == 1 ? o1 : o2)) + (long)h * D * DIN;
    int c0 = blockIdx.x * 32, r0 = blockIdx.y * 32;
    int lx = threadIdx.x & 31, ly = threadIdx.x >> 5;  // 32 x 8
#pragma unroll
    for (int i = 0; i < 32; i += 8) t[ly + i][lx] = src[(long)(r0 + ly + i) * D + c0 + lx];
    __syncthreads();
#pragma unroll
    for (int i = 0; i < 32; i += 8) dst[(long)(c0 + ly + i) * DIN + r0 + lx] = (bf16)t[lx][ly + i];
}

__global__ __launch_bounds__(256) void transpose_cvt_sq(const float* __restrict__ in,
                                                        bf16* __restrict__ out, int N) {
    __shared__ float t[32][33];
    int c0 = blockIdx.x * 32, r0 = blockIdx.y * 32;
    int lx = threadIdx.x & 31, ly = threadIdx.x >> 5;
#pragma unroll
    for (int i = 0; i < 32; i += 8) t[ly + i][lx] = in[(long)(r0 + ly + i) * N + c0 + lx];
    __syncthreads();
#pragma unroll
    for (int i = 0; i < 32; i += 8) out[(long)(c0 + ly + i) * N + r0 + lx] = (bf16)t[lx][ly + i];
}

// ---------------- fused QKV projection GEMM, m97-style LDS staging ----------------
// grid (24, 32): bx>>3 selects {Q,K,V}; tile 128x128, 4 waves, BK=32.
// Q output folds 0.125*log2e (exp2-domain softmax); V written transposed [hb][e][s]
// via an LDS re-stage so stores are 128B-contiguous instead of 2B @ 4KB stride.
__global__ __launch_bounds__(256) void qkv_gemm(const bf16* __restrict__ Aq, const bf16* __restrict__ Ak,
                                                const bf16* __restrict__ Av,
                                                const bf16* __restrict__ Wq_, const bf16* __restrict__ Wk_,
                                                const bf16* __restrict__ Wv_,
                                                const float* __restrict__ bq_, const float* __restrict__ bk_,
                                                const float* __restrict__ bv_,
                                                bf16* __restrict__ Qp, bf16* __restrict__ Kp,
                                                bf16* __restrict__ Vt) {
    // smem: first 8192 elems = As(128x32) + Bs(128x32) staging; full 128*136 for V^T re-stage
    __shared__ __align__(16) bf16 smem[128 * 136];
    bf16* As = smem;
    bf16* Bs = smem + 128 * 32;
    int lane = threadIdx.x & 63, wid = threadIdx.x >> 6;
    int li = lane & 15, lg = lane >> 4;
    int bx = blockIdx.x, by = blockIdx.y;
    int which = bx >> 3;
    const bf16* A = which == 0 ? Aq : (which == 1 ? Ak : Av);
    const bf16* W = which == 0 ? Wq_ : (which == 1 ? Wk_ : Wv_);
    const float* bias = which == 0 ? bq_ : (which == 1 ? bk_ : bv_);
    float scale = which == 0 ? 0.125f * LOG2E : 1.0f;

    int am0 = by * 128;        // global m base of A tile
    int bn0 = (bx & 7) * 128;  // n base within this weight
    int srow = lane >> 2, scol = (lane & 3) * 8;  // lane -> (row, col) in 16-row staging chunk

    f32x4 acc[4][4];
#pragma unroll
    for (int i = 0; i < 4; i++)
#pragma unroll
        for (int j = 0; j < 4; j++) acc[i][j] = (f32x4){0.f, 0.f, 0.f, 0.f};

    for (int k0 = 0; k0 < DIN; k0 += 32) {
#pragma unroll
        for (int t = 0; t < 2; t++) {
            int r = (wid * 2 + t) * 16;  // 16-row chunk per wave-inst, 8 chunks cover 128 rows
            gld16(A + (long)(am0 + r + srow) * DIN + k0 + scol, &As[r * 32], lane);
            gld16(W + (long)(bn0 + r + srow) * DIN + k0 + scol, &Bs[r * 32], lane);
        }
        __syncthreads();
        bf16x8 af[4], bfr[4];
#pragma unroll
        for (int i = 0; i < 4; i++)
            af[i] = *(const bf16x8*)&As[((wid >> 1) * 64 + i * 16 + li) * 32 + lg * 8];
#pragma unroll
        for (int j = 0; j < 4; j++)
            bfr[j] = *(const bf16x8*)&Bs[((wid & 1) * 64 + j * 16 + li) * 32 + lg * 8];
#pragma unroll
        for (int i = 0; i < 4; i++)
#pragma unroll
            for (int j = 0; j < 4; j++)
                acc[i][j] = __builtin_amdgcn_mfma_f32_16x16x32_bf16(af[i], bfr[j], acc[i][j], 0, 0, 0);
        __syncthreads();
    }

    int bb = am0 >> 11;       // batch index (tile never straddles the S boundary)
    int s0 = am0 & 2047;      // within-batch sequence base  (FIX: was am0 unmasked)
    if (which == 2) {
        // ---- V: stage C^T into LDS [n_local][m_local], then coalesced row writes ----
#pragma unroll
        for (int i = 0; i < 4; i++)
#pragma unroll
            for (int j = 0; j < 4; j++) {
                int nl = (wid & 1) * 64 + j * 16 + li;
                float bv = bias[bn0 + nl];
#pragma unroll
                for (int r = 0; r < 4; r++) {
                    int ml = (wid >> 1) * 64 + i * 16 + lg * 4 + r;
                    smem[nl * 136 + ml] = (bf16)(acc[i][j][r] + bv);
                }
            }
        __syncthreads();
        int t = threadIdx.x, row = t >> 1, half = t & 1;
        int n = bn0 + row, hh = n >> 6, e = n & 63;
        bf16* dst = Vt + (((long)hh * NB + bb) * D + e) * S + s0 + half * 64;
        const bf16* srcp = &smem[row * 136 + half * 64];
#pragma unroll
        for (int k2 = 0; k2 < 8; k2++)
            *(bf16x8*)(dst + k2 * 8) = *(const bf16x8*)(srcp + k2 * 8);
    } else {
        bf16* outp = which == 0 ? Qp : Kp;
#pragma unroll
        for (int i = 0; i < 4; i++) {
#pragma unroll
            for (int j = 0; j < 4; j++) {
                int n = bn0 + (wid & 1) * 64 + j * 16 + li;  // 0..1023 within weight
                float bv = bias[n];
                int h = n >> 6, e = n & 63;
#pragma unroll
                for (int r = 0; r < 4; r++) {
                    int m = am0 + (wid >> 1) * 64 + i * 16 + lg * 4 + r;
                    int s = m & 2047;
                    float v = (acc[i][j][r] + bv) * scale;
                    outp[(((long)h * NB + bb) * S + s) * D + e] = (bf16)v;
                }
            }
        }
    }
}

// ---------------- flash attention: 1024 blocks x 64 q-rows (4 waves x 16 rows) ----------------
// KVBLK=64, defer-max, exp2 domain, XCD swizzle.
// Qp/Kp: bf16 [hb][S][64] (Q pre-scaled by 0.125*log2e); VT: bf16 [hb][64][S]; cat: bf16 [b][s][h*64+e]
__global__ __launch_bounds__(256) void attn_kernel(const bf16* __restrict__ Qp,
                                                   const bf16* __restrict__ Kp,
                                                   const bf16* __restrict__ VT,
                                                   bf16* __restrict__ cat) {
    __shared__ __align__(16) bf16 plds[4][16][72];  // per-wave P buffer (16 rows x 64, stride 72)
    int lane = threadIdx.x & 63, wid = threadIdx.x >> 6;
    int li = lane & 15, lg = lane >> 4;
    // XCD-aware chunked swizzle: 1024 blocks -> 128 contiguous per XCD (4 hb = 2MB KV per L2)
    int bid = blockIdx.x;
    int swz = (bid & 7) * 128 + (bid >> 3);
    int hb = swz >> 5, qb = swz & 31;
    int h = hb >> 1, b = hb & 1;
    int q0 = qb * 64 + wid * 16;

    const bf16* Qb = Qp + (long)hb * S * D;
    const bf16* Kb = Kp + (long)hb * S * D;
    const bf16* Vb = VT + (long)hb * D * S;

    // hoist Q fragments (16 rows x 64 e per wave)
    bf16x8 qf[2];
#pragma unroll
    for (int ke = 0; ke < 2; ke++)
        qf[ke] = *(const bf16x8*)(Qb + (q0 + li) * D + ke * 32 + lg * 8);

    f32x4 o[4];
    float mrow[4], lrow[4];
#pragma unroll
    for (int ef = 0; ef < 4; ef++) o[ef] = (f32x4){0.f, 0.f, 0.f, 0.f};
#pragma unroll
    for (int r = 0; r < 4; r++) { mrow[r] = -INFINITY; lrow[r] = 0.f; }

    for (int t0 = 0; t0 < S; t0 += 64) {
        // ---- scores: S[16 rows][64 t] per wave (exp2 domain) ----
        f32x4 sf[4];
#pragma unroll
        for (int tf = 0; tf < 4; tf++) sf[tf] = (f32x4){0.f, 0.f, 0.f, 0.f};
        bf16x8 kf[4][2];
#pragma unroll
        for (int tf = 0; tf < 4; tf++)
#pragma unroll
            for (int ke = 0; ke < 2; ke++)
                kf[tf][ke] = *(const bf16x8*)(Kb + (t0 + tf * 16 + li) * D + ke * 32 + lg * 8);
        __builtin_amdgcn_s_setprio(1);
#pragma unroll
        for (int tf = 0; tf < 4; tf++)
#pragma unroll
            for (int ke = 0; ke < 2; ke++)
                sf[tf] = __builtin_amdgcn_mfma_f32_16x16x32_bf16(qf[ke], kf[tf][ke], sf[tf], 0, 0, 0);
        __builtin_amdgcn_s_setprio(0);

        // ---- tile max per row (rows live in (lg,r); cols in li across 16 lanes) ----
        float pm[4];
#pragma unroll
        for (int r = 0; r < 4; r++)
            pm[r] = fmaxf(fmaxf(sf[0][r], sf[1][r]), fmaxf(sf[2][r], sf[3][r]));
#pragma unroll
        for (int mask = 1; mask <= 8; mask <<= 1)
#pragma unroll
            for (int r = 0; r < 4; r++) pm[r] = fmaxf(pm[r], __shfl_xor(pm[r], mask));
        float dm = -INFINITY;
#pragma unroll
        for (int r = 0; r < 4; r++) dm = fmaxf(dm, pm[r] - mrow[r]);

        if (__all(dm <= 11.5f)) {
            // defer-max: keep old running max, no rescale (P bounded by 2^11.5)
            float rs[4] = {0.f, 0.f, 0.f, 0.f};
#pragma unroll
            for (int tf = 0; tf < 4; tf++)
#pragma unroll
                for (int r = 0; r < 4; r++) {
                    float p = exp2_hw(sf[tf][r] - mrow[r]);
                    sf[tf][r] = p;
                    rs[r] += p;
                }
#pragma unroll
            for (int mask = 1; mask <= 8; mask <<= 1)
#pragma unroll
                for (int r = 0; r < 4; r++) rs[r] += __shfl_xor(rs[r], mask);
#pragma unroll
            for (int r = 0; r < 4; r++) lrow[r] += rs[r];
        } else {
            float cr[4];
#pragma unroll
            for (int r = 0; r < 4; r++) {
                float mn = fmaxf(mrow[r], pm[r]);
                cr[r] = exp2_hw(mrow[r] - mn);
                mrow[r] = mn;
            }
            float rs[4] = {0.f, 0.f, 0.f, 0.f};
#pragma unroll
            for (int tf = 0; tf < 4; tf++)
#pragma unroll
                for (int r = 0; r < 4; r++) {
                    float p = exp2_hw(sf[tf][r] - mrow[r]);
                    sf[tf][r] = p;
                    rs[r] += p;
                }
#pragma unroll
            for (int mask = 1; mask <= 8; mask <<= 1)
#pragma unroll
                for (int r = 0; r < 4; r++) rs[r] += __shfl_xor(rs[r], mask);
#pragma unroll
            for (int r = 0; r < 4; r++) lrow[r] = lrow[r] * cr[r] + rs[r];
#pragma unroll
            for (int ef = 0; ef < 4; ef++)
#pragma unroll
                for (int r = 0; r < 4; r++) o[ef][r] *= cr[r];
        }

        // ---- transpose P through per-wave LDS into A-fragment layout ----
#pragma unroll
        for (int tf = 0; tf < 4; tf++)
#pragma unroll
            for (int r = 0; r < 4; r++)
                plds[wid][lg * 4 + r][tf * 16 + li] = (bf16)sf[tf][r];
        asm volatile("s_waitcnt lgkmcnt(0)" ::: "memory");

        bf16x8 vf[4][2], pf[2];
#pragma unroll
        for (int ef = 0; ef < 4; ef++)
#pragma unroll
            for (int ks = 0; ks < 2; ks++)
                vf[ef][ks] = *(const bf16x8*)(Vb + (ef * 16 + li) * S + t0 + ks * 32 + lg * 8);
#pragma unroll
        for (int ks = 0; ks < 2; ks++)
            pf[ks] = *(const bf16x8*)&plds[wid][li][ks * 32 + lg * 8];
        __builtin_amdgcn_s_setprio(1);
#pragma unroll
        for (int ef = 0; ef < 4; ef++)
#pragma unroll
            for (int ks = 0; ks < 2; ks++)
                o[ef] = __builtin_amdgcn_mfma_f32_16x16x32_bf16(pf[ks], vf[ef][ks], o[ef], 0, 0, 0);
        __builtin_amdgcn_s_setprio(0);
    }

    // ---- epilogue: divide by l, write cat[b][s][h*64+e] ----
#pragma unroll
    for (int r = 0; r < 4; r++) {
        float inv = 1.0f / lrow[r];
        int s = q0 + lg * 4 + r;
#pragma unroll
        for (int ef = 0; ef < 4; ef++)
            cat[((long)b * S + s) * (H * D) + h * D + ef * 16 + li] = (bf16)(o[ef][r] * inv);
    }
}

// ---------------- output projection, LDS-staged, tile 128x64, grid (16,32) ----------------
__global__ __launch_bounds__(256) void out_gemm(const bf16* __restrict__ A,
                                                const bf16* __restrict__ WoT,
                                                const float* __restrict__ bo,
                                                float* __restrict__ out) {
    __shared__ bf16 As[128 * 32], Bs[64 * 32];
    int lane = threadIdx.x & 63, wid = threadIdx.x >> 6;
    int li = lane & 15, lg = lane >> 4;
    int am0 = blockIdx.y * 128, bn0 = blockIdx.x * 64;
    int srow = lane >> 2, scol = (lane & 3) * 8;

    f32x4 acc[4][2];
#pragma unroll
    for (int i = 0; i < 4; i++)
#pragma unroll
        for (int j = 0; j < 2; j++) acc[i][j] = (f32x4){0.f, 0.f, 0.f, 0.f};

    for (int k0 = 0; k0 < DIN; k0 += 32) {
#pragma unroll
        for (int t = 0; t < 2; t++) {
            int r = (wid * 2 + t) * 16;
            gld16(A + (long)(am0 + r + srow) * DIN + k0 + scol, &As[r * 32], lane);
        }
        gld16(WoT + (long)(bn0 + wid * 16 + srow) * DIN + k0 + scol, &Bs[wid * 16 * 32], lane);
        __syncthreads();
        bf16x8 af[4], bfr[2];
#pragma unroll
        for (int i = 0; i < 4; i++)
            af[i] = *(const bf16x8*)&As[((wid >> 1) * 64 + i * 16 + li) * 32 + lg * 8];
#pragma unroll
        for (int j = 0; j < 2; j++)
            bfr[j] = *(const bf16x8*)&Bs[((wid & 1) * 32 + j * 16 + li) * 32 + lg * 8];
#pragma unroll
        for (int i = 0; i < 4; i++)
#pragma unroll
            for (int j = 0; j < 2; j++)
                acc[i][j] = __builtin_amdgcn_mfma_f32_16x16x32_bf16(af[i], bfr[j], acc[i][j], 0, 0, 0);
        __syncthreads();
    }

#pragma unroll
    for (int i = 0; i < 4; i++) {
#pragma unroll
        for (int j = 0; j < 2; j++) {
            int n = bn0 + (wid & 1) * 32 + j * 16 + li;
            float bv = bo[n];
#pragma unroll
            for (int r = 0; r < 4; r++) {
                int m = am0 + (wid >> 1) * 64 + i * 16 + lg * 4 + r;
                out[(long)m * DIN + n] = acc[i][j][r] + bv;
            }
        }
    }
}

extern "C" void kernel_launch(void* const* d_in, const int* in_sizes, int n_in,
                              void* d_out, int out_size, void* d_ws, size_t ws_size,
                              hipStream_t stream) {
    const float* query = (const float*)d_in[0];
    const float* key_  = (const float*)d_in[1];
    const float* value = (const float*)d_in[2];
    const float* Wq = (const float*)d_in[3];
    const float* bq = (const float*)d_in[4];
    const float* Wk = (const float*)d_in[5];
    const float* bk = (const float*)d_in[6];
    const float* Wv = (const float*)d_in[7];
    const float* bv = (const float*)d_in[8];
    const float* Wo = (const float*)d_in[9];
    const float* bo = (const float*)d_in[10];
    float* out = (float*)d_out;

    char* w = (char*)d_ws;
    size_t off = 0;
    auto take = [&](size_t bytes) -> char* {
        char* p = w + off;
        off += (bytes + 255) & ~(size_t)255;
        return p;
    };
    bf16* Xbq = (bf16*)take((size_t)BS * DIN * 2);
    bf16* Xbk = (bf16*)take((size_t)BS * DIN * 2);
    bf16* Xbv = (bf16*)take((size_t)BS * DIN * 2);
    bf16* WqT = (bf16*)take((size_t)H * D * DIN * 2);
    bf16* WkT = (bf16*)take((size_t)H * D * DIN * 2);
    bf16* WvT = (bf16*)take((size_t)H * D * DIN * 2);
    bf16* WoT = (bf16*)take((size_t)DIN * (H * D) * 2);
    bf16* Qp  = (bf16*)take((size_t)H * NB * S * D * 2);
    bf16* Kp  = (bf16*)take((size_t)H * NB * S * D * 2);
    bf16* VTs = (bf16*)take((size_t)H * NB * D * S * 2);
    bf16* cat = (bf16*)take((size_t)BS * (H * D) * 2);

    int n4 = BS * DIN / 4;
    cvt3_f32_bf16<<<dim3(n4 / 256, 3), 256, 0, stream>>>(
        (const float4*)query, (const float4*)key_, (const float4*)value,
        (bf16x4*)Xbq, (bf16x4*)Xbk, (bf16x4*)Xbv, n4);

    transpose3_cvt<<<dim3(D / 32, DIN / 32, 3 * H), 256, 0, stream>>>(Wq, Wk, Wv, WqT, WkT, WvT);
    transpose_cvt_sq<<<dim3(DIN / 32, DIN / 32), 256, 0, stream>>>(Wo, WoT, DIN);

    qkv_gemm<<<dim3(24, 32), 256, 0, stream>>>(Xbq, Xbk, Xbv, WqT, WkT, WvT, bq, bk, bv, Qp, Kp, VTs);

    attn_kernel<<<dim3(1024), 256, 0, stream>>>(Qp, Kp, VTs, cat);

    out_gemm<<<dim3(16, 32), 256, 0, stream>>>(cat, WoT, bo, out);
}

// Round 14
// 289.786 us; speedup vs baseline: 1.4142x; 1.4142x over previous
//
#include <hip/hip_runtime.h>
#include <hip/hip_bf16.h>
#include <cmath>

typedef __bf16 bf16;
typedef bf16 bf16x4 __attribute__((ext_vector_type(4)));
typedef bf16 bf16x8 __attribute__((ext_vector_type(8)));
typedef float f32x4 __attribute__((ext_vector_type(4)));

constexpr int H = 16, DIN = 1024, D = 64, NB = 2, S = 2048;
constexpr int BS = NB * S;  // 4096 rows
constexpr float LOG2E = 1.4426950408889634f;

// exp2: lowers to a single v_exp_f32 (HW exp is base-2)
__device__ __forceinline__ float exp2_hw(float x) {
#if __has_builtin(__builtin_amdgcn_exp2f)
    return __builtin_amdgcn_exp2f(x);
#else
    return exp2f(x);
#endif
}

// async global->LDS, 16B per lane; dest = wave-uniform base + lane*16
__device__ __forceinline__ void gld16(const bf16* g, bf16* lbase, int lane) {
#if __has_builtin(__builtin_amdgcn_global_load_lds)
    __builtin_amdgcn_global_load_lds((const __attribute__((address_space(1))) unsigned int*)g,
                                     (__attribute__((address_space(3))) unsigned int*)lbase,
                                     16, 0, 0);
#else
    *(float4*)((char*)lbase + lane * 16) = *(const float4*)g;
#endif
}

// ---------------- fp32 -> bf16 elementwise convert, 3 tensors in one dispatch ----------------
__global__ __launch_bounds__(256) void cvt3_f32_bf16(const float4* __restrict__ in0,
                                                     const float4* __restrict__ in1,
                                                     const float4* __restrict__ in2,
                                                     bf16x4* __restrict__ out0,
                                                     bf16x4* __restrict__ out1,
                                                     bf16x4* __restrict__ out2, int n4) {
    int i = blockIdx.x * 256 + threadIdx.x;
    if (i >= n4) return;
    const float4* in = blockIdx.y == 0 ? in0 : (blockIdx.y == 1 ? in1 : in2);
    bf16x4* out = blockIdx.y == 0 ? out0 : (blockIdx.y == 1 ? out1 : out2);
    float4 v = in[i];
    bf16x4 o = {(bf16)v.x, (bf16)v.y, (bf16)v.z, (bf16)v.w};
    out[i] = o;
}

// ---------------- transpose + convert: per-head Wq/Wk/Wv [DIN][64] -> [64][DIN] ----------------
__global__ __launch_bounds__(256) void transpose3_cvt(const float* __restrict__ w0,
                                                      const float* __restrict__ w1,
                                                      const float* __restrict__ w2,
                                                      bf16* __restrict__ o0,
                                                      bf16* __restrict__ o1,
                                                      bf16* __restrict__ o2) {
    __shared__ float t[32][33];
    int z = blockIdx.z, which = z / H, h = z % H;
    const float* src = (which == 0 ? w0 : (which == 1 ? w1 : w2)) + (long)h * DIN * D;
    bf16* dst = (which == 0 ? o0 : (which == 1 ? o1 : o2)) + (long)h * D * DIN;
    int c0 = blockIdx.x * 32, r0 = blockIdx.y * 32;
    int lx = threadIdx.x & 31, ly = threadIdx.x >> 5;  // 32 x 8
#pragma unroll
    for (int i = 0; i < 32; i += 8) t[ly + i][lx] = src[(long)(r0 + ly + i) * D + c0 + lx];
    __syncthreads();
#pragma unroll
    for (int i = 0; i < 32; i += 8) dst[(long)(c0 + ly + i) * DIN + r0 + lx] = (bf16)t[lx][ly + i];
}

__global__ __launch_bounds__(256) void transpose_cvt_sq(const float* __restrict__ in,
                                                        bf16* __restrict__ out, int N) {
    __shared__ float t[32][33];
    int c0 = blockIdx.x * 32, r0 = blockIdx.y * 32;
    int lx = threadIdx.x & 31, ly = threadIdx.x >> 5;
#pragma unroll
    for (int i = 0; i < 32; i += 8) t[ly + i][lx] = in[(long)(r0 + ly + i) * N + c0 + lx];
    __syncthreads();
#pragma unroll
    for (int i = 0; i < 32; i += 8) out[(long)(c0 + ly + i) * N + r0 + lx] = (bf16)t[lx][ly + i];
}

// ---------------- fused QKV projection GEMM, m97-style LDS staging ----------------
__global__ __launch_bounds__(256) void qkv_gemm(const bf16* __restrict__ Aq, const bf16* __restrict__ Ak,
                                                const bf16* __restrict__ Av,
                                                const bf16* __restrict__ Wq_, const bf16* __restrict__ Wk_,
                                                const bf16* __restrict__ Wv_,
                                                const float* __restrict__ bq_, const float* __restrict__ bk_,
                                                const float* __restrict__ bv_,
                                                bf16* __restrict__ Qp, bf16* __restrict__ Kp,
                                                bf16* __restrict__ Vt) {
    __shared__ __align__(16) bf16 smem[128 * 136];
    bf16* As = smem;
    bf16* Bs = smem + 128 * 32;
    int lane = threadIdx.x & 63, wid = threadIdx.x >> 6;
    int li = lane & 15, lg = lane >> 4;
    int bx = blockIdx.x, by = blockIdx.y;
    int which = bx >> 3;
    const bf16* A = which == 0 ? Aq : (which == 1 ? Ak : Av);
    const bf16* W = which == 0 ? Wq_ : (which == 1 ? Wk_ : Wv_);
    const float* bias = which == 0 ? bq_ : (which == 1 ? bk_ : bv_);
    float scale = which == 0 ? 0.125f * LOG2E : 1.0f;

    int am0 = by * 128;
    int bn0 = (bx & 7) * 128;
    int srow = lane >> 2, scol = (lane & 3) * 8;

    f32x4 acc[4][4];
#pragma unroll
    for (int i = 0; i < 4; i++)
#pragma unroll
        for (int j = 0; j < 4; j++) acc[i][j] = (f32x4){0.f, 0.f, 0.f, 0.f};

    for (int k0 = 0; k0 < DIN; k0 += 32) {
#pragma unroll
        for (int t = 0; t < 2; t++) {
            int r = (wid * 2 + t) * 16;
            gld16(A + (long)(am0 + r + srow) * DIN + k0 + scol, &As[r * 32], lane);
            gld16(W + (long)(bn0 + r + srow) * DIN + k0 + scol, &Bs[r * 32], lane);
        }
        __syncthreads();
        bf16x8 af[4], bfr[4];
#pragma unroll
        for (int i = 0; i < 4; i++)
            af[i] = *(const bf16x8*)&As[((wid >> 1) * 64 + i * 16 + li) * 32 + lg * 8];
#pragma unroll
        for (int j = 0; j < 4; j++)
            bfr[j] = *(const bf16x8*)&Bs[((wid & 1) * 64 + j * 16 + li) * 32 + lg * 8];
#pragma unroll
        for (int i = 0; i < 4; i++)
#pragma unroll
            for (int j = 0; j < 4; j++)
                acc[i][j] = __builtin_amdgcn_mfma_f32_16x16x32_bf16(af[i], bfr[j], acc[i][j], 0, 0, 0);
        __syncthreads();
    }

    int bb = am0 >> 11;
    int s0 = am0 & 2047;
    if (which == 2) {
        // V: stage C^T into LDS, then coalesced row writes
#pragma unroll
        for (int i = 0; i < 4; i++)
#pragma unroll
            for (int j = 0; j < 4; j++) {
                int nl = (wid & 1) * 64 + j * 16 + li;
                float bv = bias[bn0 + nl];
#pragma unroll
                for (int r = 0; r < 4; r++) {
                    int ml = (wid >> 1) * 64 + i * 16 + lg * 4 + r;
                    smem[nl * 136 + ml] = (bf16)(acc[i][j][r] + bv);
                }
            }
        __syncthreads();
        int t = threadIdx.x, row = t >> 1, half = t & 1;
        int n = bn0 + row, hh = n >> 6, e = n & 63;
        bf16* dst = Vt + (((long)hh * NB + bb) * D + e) * S + s0 + half * 64;
        const bf16* srcp = &smem[row * 136 + half * 64];
#pragma unroll
        for (int k2 = 0; k2 < 8; k2++)
            *(bf16x8*)(dst + k2 * 8) = *(const bf16x8*)(srcp + k2 * 8);
    } else {
        bf16* outp = which == 0 ? Qp : Kp;
#pragma unroll
        for (int i = 0; i < 4; i++) {
#pragma unroll
            for (int j = 0; j < 4; j++) {
                int n = bn0 + (wid & 1) * 64 + j * 16 + li;
                float bv = bias[n];
                int h = n >> 6, e = n & 63;
#pragma unroll
                for (int r = 0; r < 4; r++) {
                    int m = am0 + (wid >> 1) * 64 + i * 16 + lg * 4 + r;
                    int s = m & 2047;
                    float v = (acc[i][j][r] + bv) * scale;
                    outp[(((long)h * NB + bb) * S + s) * D + e] = (bf16)v;
                }
            }
        }
    }
}

// ---------------- flash attention: 512 blocks, 4 waves x 32 q-rows, block-shared LDS K/V ----------------
// K/V staged once per block (double-buffered, XOR-source-swizzled so ds_read_b128 is conflict-free).
// Qp/Kp: bf16 [hb][S][64] (Q pre-scaled by 0.125*log2e); VT: bf16 [hb][64][S]; cat: bf16 [b][s][h*64+e]
__global__ __launch_bounds__(256) void attn_kernel(const bf16* __restrict__ Qp,
                                                   const bf16* __restrict__ Kp,
                                                   const bf16* __restrict__ VT,
                                                   bf16* __restrict__ cat) {
    __shared__ __align__(16) bf16 Ks[2][64 * 64];   // linear [row][64], rows 128B, XOR-swizzled content
    __shared__ __align__(16) bf16 Vs[2][64 * 64];   // linear [e][64 s-cols of tile]
    __shared__ __align__(16) bf16 plds[4][32][72];  // per-wave P buffer
    int lane = threadIdx.x & 63, wid = threadIdx.x >> 6;
    int li = lane & 15, lg = lane >> 4;
    // XCD-aware chunked swizzle: 512 blocks -> 64 contiguous per XCD (4 hb = 2MB KV per L2)
    int bid = blockIdx.x;
    int swz = (bid & 7) * 64 + (bid >> 3);
    int hb = swz >> 4, qb = swz & 15;
    int h = hb >> 1, b = hb & 1;
    int q0 = qb * 128 + wid * 32;

    const bf16* Qb = Qp + (long)hb * S * D;
    const bf16* Kb = Kp + (long)hb * S * D;
    const bf16* Vb = VT + (long)hb * D * S;

    // staging lane map: each gld16 covers 8 rows (1KB). lane l -> row l>>3, physical chunk l&7.
    // source fetches LOGICAL chunk (l&7)^(l>>3)  => reader XORs chunk with (row&7). conflict-free b128.
    int srow8 = lane >> 3, lc16 = (lane & 7) ^ srow8;

    // hoist Q fragments (32 rows x 64 e per wave)
    bf16x8 qf[2][2];
#pragma unroll
    for (int rf = 0; rf < 2; rf++)
#pragma unroll
        for (int ke = 0; ke < 2; ke++)
            qf[rf][ke] = *(const bf16x8*)(Qb + (q0 + rf * 16 + li) * D + ke * 32 + lg * 8);

    f32x4 o[2][4];
    float mrow[2][4], lrow[2][4];
#pragma unroll
    for (int rf = 0; rf < 2; rf++) {
#pragma unroll
        for (int ef = 0; ef < 4; ef++) o[rf][ef] = (f32x4){0.f, 0.f, 0.f, 0.f};
#pragma unroll
        for (int r = 0; r < 4; r++) { mrow[rf][r] = -INFINITY; lrow[rf][r] = 0.f; }
    }

    // prologue: stage tile 0 (wave wid stages rows [wid*16, wid*16+16) of both K and V)
#pragma unroll
    for (int w = 0; w < 2; w++) {
        int rb = wid * 16 + w * 8;
        gld16(Kb + (long)(rb + srow8) * D + lc16 * 8, &Ks[0][rb * 64], lane);
        gld16(Vb + (long)(rb + srow8) * S + 0 + lc16 * 8, &Vs[0][rb * 64], lane);
    }
    __syncthreads();
    int buf = 0;

    for (int t0 = 0; t0 < S; t0 += 64) {
        // ---- issue next-tile staging (hides under compute; barrier at loop end drains) ----
        if (t0 + 64 < S) {
#pragma unroll
            for (int w = 0; w < 2; w++) {
                int rb = wid * 16 + w * 8;
                gld16(Kb + (long)(t0 + 64 + rb + srow8) * D + lc16 * 8, &Ks[buf ^ 1][rb * 64], lane);
                gld16(Vb + (long)(rb + srow8) * S + t0 + 64 + lc16 * 8, &Vs[buf ^ 1][rb * 64], lane);
            }
        }

        // ---- K fragments from LDS (swizzled read) ----
        bf16x8 kf[4][2];
#pragma unroll
        for (int tf = 0; tf < 4; tf++)
#pragma unroll
            for (int ke = 0; ke < 2; ke++)
                kf[tf][ke] = *(const bf16x8*)&Ks[buf][(tf * 16 + li) * 64 + (((ke * 4 + lg) ^ (li & 7)) << 3)];

        f32x4 sf[2][4];
#pragma unroll
        for (int rf = 0; rf < 2; rf++)
#pragma unroll
            for (int tf = 0; tf < 4; tf++) sf[rf][tf] = (f32x4){0.f, 0.f, 0.f, 0.f};
        __builtin_amdgcn_s_setprio(1);
#pragma unroll
        for (int rf = 0; rf < 2; rf++)
#pragma unroll
            for (int tf = 0; tf < 4; tf++)
#pragma unroll
                for (int ke = 0; ke < 2; ke++)
                    sf[rf][tf] = __builtin_amdgcn_mfma_f32_16x16x32_bf16(qf[rf][ke], kf[tf][ke], sf[rf][tf], 0, 0, 0);
        __builtin_amdgcn_s_setprio(0);

        // ---- online softmax (rows in (lg,r); cols in li across 16 lanes) ----
        float pm[2][4];
#pragma unroll
        for (int rf = 0; rf < 2; rf++) {
#pragma unroll
            for (int r = 0; r < 4; r++)
                pm[rf][r] = fmaxf(fmaxf(sf[rf][0][r], sf[rf][1][r]), fmaxf(sf[rf][2][r], sf[rf][3][r]));
#pragma unroll
            for (int mask = 1; mask <= 8; mask <<= 1)
#pragma unroll
                for (int r = 0; r < 4; r++) pm[rf][r] = fmaxf(pm[rf][r], __shfl_xor(pm[rf][r], mask));
        }
        float dm = -INFINITY;
#pragma unroll
        for (int rf = 0; rf < 2; rf++)
#pragma unroll
            for (int r = 0; r < 4; r++) dm = fmaxf(dm, pm[rf][r] - mrow[rf][r]);

        if (__all(dm <= 11.5f)) {
            // defer-max: keep old running max, no rescale (P bounded by 2^11.5)
#pragma unroll
            for (int rf = 0; rf < 2; rf++) {
                float rs[4] = {0.f, 0.f, 0.f, 0.f};
#pragma unroll
                for (int tf = 0; tf < 4; tf++)
#pragma unroll
                    for (int r = 0; r < 4; r++) {
                        float p = exp2_hw(sf[rf][tf][r] - mrow[rf][r]);
                        sf[rf][tf][r] = p;
                        rs[r] += p;
                    }
#pragma unroll
                for (int mask = 1; mask <= 8; mask <<= 1)
#pragma unroll
                    for (int r = 0; r < 4; r++) rs[r] += __shfl_xor(rs[r], mask);
#pragma unroll
                for (int r = 0; r < 4; r++) lrow[rf][r] += rs[r];
            }
        } else {
#pragma unroll
            for (int rf = 0; rf < 2; rf++) {
                float cr[4];
#pragma unroll
                for (int r = 0; r < 4; r++) {
                    float mn = fmaxf(mrow[rf][r], pm[rf][r]);
                    cr[r] = exp2_hw(mrow[rf][r] - mn);
                    mrow[rf][r] = mn;
                }
                float rs[4] = {0.f, 0.f, 0.f, 0.f};
#pragma unroll
                for (int tf = 0; tf < 4; tf++)
#pragma unroll
                    for (int r = 0; r < 4; r++) {
                        float p = exp2_hw(sf[rf][tf][r] - mrow[rf][r]);
                        sf[rf][tf][r] = p;
                        rs[r] += p;
                    }
#pragma unroll
                for (int mask = 1; mask <= 8; mask <<= 1)
#pragma unroll
                    for (int r = 0; r < 4; r++) rs[r] += __shfl_xor(rs[r], mask);
#pragma unroll
                for (int r = 0; r < 4; r++) lrow[rf][r] = lrow[rf][r] * cr[r] + rs[r];
#pragma unroll
                for (int ef = 0; ef < 4; ef++)
#pragma unroll
                    for (int r = 0; r < 4; r++) o[rf][ef][r] *= cr[r];
            }
        }

        // ---- transpose P through per-wave LDS into A-fragment layout ----
#pragma unroll
        for (int rf = 0; rf < 2; rf++)
#pragma unroll
            for (int tf = 0; tf < 4; tf++)
#pragma unroll
                for (int r = 0; r < 4; r++)
                    plds[wid][rf * 16 + lg * 4 + r][tf * 16 + li] = (bf16)sf[rf][tf][r];
        asm volatile("s_waitcnt lgkmcnt(0)" ::: "memory");

        // ---- V fragments from LDS (swizzled read) + PV ----
        bf16x8 vf[4][2], pf[2][2];
#pragma unroll
        for (int ef = 0; ef < 4; ef++)
#pragma unroll
            for (int ks = 0; ks < 2; ks++)
                vf[ef][ks] = *(const bf16x8*)&Vs[buf][(ef * 16 + li) * 64 + (((ks * 4 + lg) ^ (li & 7)) << 3)];
#pragma unroll
        for (int rf = 0; rf < 2; rf++)
#pragma unroll
            for (int ks = 0; ks < 2; ks++)
                pf[rf][ks] = *(const bf16x8*)&plds[wid][rf * 16 + li][ks * 32 + lg * 8];
        __builtin_amdgcn_s_setprio(1);
#pragma unroll
        for (int rf = 0; rf < 2; rf++)
#pragma unroll
            for (int ef = 0; ef < 4; ef++)
#pragma unroll
                for (int ks = 0; ks < 2; ks++)
                    o[rf][ef] = __builtin_amdgcn_mfma_f32_16x16x32_bf16(pf[rf][ks], vf[ef][ks], o[rf][ef], 0, 0, 0);
        __builtin_amdgcn_s_setprio(0);

        __syncthreads();  // drains vmcnt (next-tile staging) + lgkm; all waves done with buf
        buf ^= 1;
    }

    // ---- epilogue: divide by l, write cat[b][s][h*64+e] ----
#pragma unroll
    for (int rf = 0; rf < 2; rf++)
#pragma unroll
        for (int r = 0; r < 4; r++) {
            float inv = 1.0f / lrow[rf][r];
            int s = q0 + rf * 16 + lg * 4 + r;
#pragma unroll
            for (int ef = 0; ef < 4; ef++)
                cat[((long)b * S + s) * (H * D) + h * D + ef * 16 + li] = (bf16)(o[rf][ef][r] * inv);
        }
}

// ---------------- output projection, LDS-staged, tile 128x64, grid (16,32) ----------------
__global__ __launch_bounds__(256) void out_gemm(const bf16* __restrict__ A,
                                                const bf16* __restrict__ WoT,
                                                const float* __restrict__ bo,
                                                float* __restrict__ out) {
    __shared__ bf16 As[128 * 32], Bs[64 * 32];
    int lane = threadIdx.x & 63, wid = threadIdx.x >> 6;
    int li = lane & 15, lg = lane >> 4;
    int am0 = blockIdx.y * 128, bn0 = blockIdx.x * 64;
    int srow = lane >> 2, scol = (lane & 3) * 8;

    f32x4 acc[4][2];
#pragma unroll
    for (int i = 0; i < 4; i++)
#pragma unroll
        for (int j = 0; j < 2; j++) acc[i][j] = (f32x4){0.f, 0.f, 0.f, 0.f};

    for (int k0 = 0; k0 < DIN; k0 += 32) {
#pragma unroll
        for (int t = 0; t < 2; t++) {
            int r = (wid * 2 + t) * 16;
            gld16(A + (long)(am0 + r + srow) * DIN + k0 + scol, &As[r * 32], lane);
        }
        gld16(WoT + (long)(bn0 + wid * 16 + srow) * DIN + k0 + scol, &Bs[wid * 16 * 32], lane);
        __syncthreads();
        bf16x8 af[4], bfr[2];
#pragma unroll
        for (int i = 0; i < 4; i++)
            af[i] = *(const bf16x8*)&As[((wid >> 1) * 64 + i * 16 + li) * 32 + lg * 8];
#pragma unroll
        for (int j = 0; j < 2; j++)
            bfr[j] = *(const bf16x8*)&Bs[((wid & 1) * 32 + j * 16 + li) * 32 + lg * 8];
#pragma unroll
        for (int i = 0; i < 4; i++)
#pragma unroll
            for (int j = 0; j < 2; j++)
                acc[i][j] = __builtin_amdgcn_mfma_f32_16x16x32_bf16(af[i], bfr[j], acc[i][j], 0, 0, 0);
        __syncthreads();
    }

#pragma unroll
    for (int i = 0; i < 4; i++) {
#pragma unroll
        for (int j = 0; j < 2; j++) {
            int n = bn0 + (wid & 1) * 32 + j * 16 + li;
            float bv = bo[n];
#pragma unroll
            for (int r = 0; r < 4; r++) {
                int m = am0 + (wid >> 1) * 64 + i * 16 + lg * 4 + r;
                out[(long)m * DIN + n] = acc[i][j][r] + bv;
            }
        }
    }
}

extern "C" void kernel_launch(void* const* d_in, const int* in_sizes, int n_in,
                              void* d_out, int out_size, void* d_ws, size_t ws_size,
                              hipStream_t stream) {
    const float* query = (const float*)d_in[0];
    const float* key_  = (const float*)d_in[1];
    const float* value = (const float*)d_in[2];
    const float* Wq = (const float*)d_in[3];
    const float* bq = (const float*)d_in[4];
    const float* Wk = (const float*)d_in[5];
    const float* bk = (const float*)d_in[6];
    const float* Wv = (const float*)d_in[7];
    const float* bv = (const float*)d_in[8];
    const float* Wo = (const float*)d_in[9];
    const float* bo = (const float*)d_in[10];
    float* out = (float*)d_out;

    char* w = (char*)d_ws;
    size_t off = 0;
    auto take = [&](size_t bytes) -> char* {
        char* p = w + off;
        off += (bytes + 255) & ~(size_t)255;
        return p;
    };
    bf16* Xbq = (bf16*)take((size_t)BS * DIN * 2);
    bf16* Xbk = (bf16*)take((size_t)BS * DIN * 2);
    bf16* Xbv = (bf16*)take((size_t)BS * DIN * 2);
    bf16* WqT = (bf16*)take((size_t)H * D * DIN * 2);
    bf16* WkT = (bf16*)take((size_t)H * D * DIN * 2);
    bf16* WvT = (bf16*)take((size_t)H * D * DIN * 2);
    bf16* WoT = (bf16*)take((size_t)DIN * (H * D) * 2);
    bf16* Qp  = (bf16*)take((size_t)H * NB * S * D * 2);
    bf16* Kp  = (bf16*)take((size_t)H * NB * S * D * 2);
    bf16* VTs = (bf16*)take((size_t)H * NB * D * S * 2);
    bf16* cat = (bf16*)take((size_t)BS * (H * D) * 2);

    int n4 = BS * DIN / 4;
    cvt3_f32_bf16<<<dim3(n4 / 256, 3), 256, 0, stream>>>(
        (const float4*)query, (const float4*)key_, (const float4*)value,
        (bf16x4*)Xbq, (bf16x4*)Xbk, (bf16x4*)Xbv, n4);

    transpose3_cvt<<<dim3(D / 32, DIN / 32, 3 * H), 256, 0, stream>>>(Wq, Wk, Wv, WqT, WkT, WvT);
    transpose_cvt_sq<<<dim3(DIN / 32, DIN / 32), 256, 0, stream>>>(Wo, WoT, DIN);

    qkv_gemm<<<dim3(24, 32), 256, 0, stream>>>(Xbq, Xbk, Xbv, WqT, WkT, WvT, bq, bk, bv, Qp, Kp, VTs);

    attn_kernel<<<dim3(512), 256, 0, stream>>>(Qp, Kp, VTs, cat);

    out_gemm<<<dim3(16, 32), 256, 0, stream>>>(cat, WoT, bo, out);
}

// Round 15
// 283.177 us; speedup vs baseline: 1.4472x; 1.0233x over previous
//
#include <hip/hip_runtime.h>
#include <hip/hip_bf16.h>
#include <cmath>

typedef __bf16 bf16;
typedef bf16 bf16x4 __attribute__((ext_vector_type(4)));
typedef bf16 bf16x8 __attribute__((ext_vector_type(8)));
typedef float f32x4 __attribute__((ext_vector_type(4)));

constexpr int H = 16, DIN = 1024, D = 64, NB = 2, S = 2048;
constexpr int BS = NB * S;  // 4096 rows
constexpr float LOG2E = 1.4426950408889634f;

// exp2: lowers to a single v_exp_f32 (HW exp is base-2)
__device__ __forceinline__ float exp2_hw(float x) {
#if __has_builtin(__builtin_amdgcn_exp2f)
    return __builtin_amdgcn_exp2f(x);
#else
    return exp2f(x);
#endif
}

// async global->LDS, 16B per lane; dest = wave-uniform base + lane*16
__device__ __forceinline__ void gld16(const bf16* g, bf16* lbase, int lane) {
#if __has_builtin(__builtin_amdgcn_global_load_lds)
    __builtin_amdgcn_global_load_lds((const __attribute__((address_space(1))) unsigned int*)g,
                                     (__attribute__((address_space(3))) unsigned int*)lbase,
                                     16, 0, 0);
#else
    *(float4*)((char*)lbase + lane * 16) = *(const float4*)g;
#endif
}

// ---------------- fp32 -> bf16 elementwise convert, 3 tensors in one dispatch ----------------
__global__ __launch_bounds__(256) void cvt3_f32_bf16(const float4* __restrict__ in0,
                                                     const float4* __restrict__ in1,
                                                     const float4* __restrict__ in2,
                                                     bf16x4* __restrict__ out0,
                                                     bf16x4* __restrict__ out1,
                                                     bf16x4* __restrict__ out2, int n4) {
    int i = blockIdx.x * 256 + threadIdx.x;
    if (i >= n4) return;
    const float4* in = blockIdx.y == 0 ? in0 : (blockIdx.y == 1 ? in1 : in2);
    bf16x4* out = blockIdx.y == 0 ? out0 : (blockIdx.y == 1 ? out1 : out2);
    float4 v = in[i];
    bf16x4 o = {(bf16)v.x, (bf16)v.y, (bf16)v.z, (bf16)v.w};
    out[i] = o;
}

// ---------------- transpose + convert: per-head Wq/Wk/Wv [DIN][64] -> [64][DIN] ----------------
__global__ __launch_bounds__(256) void transpose3_cvt(const float* __restrict__ w0,
                                                      const float* __restrict__ w1,
                                                      const float* __restrict__ w2,
                                                      bf16* __restrict__ o0,
                                                      bf16* __restrict__ o1,
                                                      bf16* __restrict__ o2) {
    __shared__ float t[32][33];
    int z = blockIdx.z, which = z / H, h = z % H;
    const float* src = (which == 0 ? w0 : (which == 1 ? w1 : w2)) + (long)h * DIN * D;
    bf16* dst = (which == 0 ? o0 : (which == 1 ? o1 : o2)) + (long)h * D * DIN;
    int c0 = blockIdx.x * 32, r0 = blockIdx.y * 32;
    int lx = threadIdx.x & 31, ly = threadIdx.x >> 5;  // 32 x 8
#pragma unroll
    for (int i = 0; i < 32; i += 8) t[ly + i][lx] = src[(long)(r0 + ly + i) * D + c0 + lx];
    __syncthreads();
#pragma unroll
    for (int i = 0; i < 32; i += 8) dst[(long)(c0 + ly + i) * DIN + r0 + lx] = (bf16)t[lx][ly + i];
}

__global__ __launch_bounds__(256) void transpose_cvt_sq(const float* __restrict__ in,
                                                        bf16* __restrict__ out, int N) {
    __shared__ float t[32][33];
    int c0 = blockIdx.x * 32, r0 = blockIdx.y * 32;
    int lx = threadIdx.x & 31, ly = threadIdx.x >> 5;
#pragma unroll
    for (int i = 0; i < 32; i += 8) t[ly + i][lx] = in[(long)(r0 + ly + i) * N + c0 + lx];
    __syncthreads();
#pragma unroll
    for (int i = 0; i < 32; i += 8) out[(long)(c0 + ly + i) * N + r0 + lx] = (bf16)t[lx][ly + i];
}

// ---------------- fused QKV projection GEMM, m97-style LDS staging ----------------
__global__ __launch_bounds__(256) void qkv_gemm(const bf16* __restrict__ Aq, const bf16* __restrict__ Ak,
                                                const bf16* __restrict__ Av,
                                                const bf16* __restrict__ Wq_, const bf16* __restrict__ Wk_,
                                                const bf16* __restrict__ Wv_,
                                                const float* __restrict__ bq_, const float* __restrict__ bk_,
                                                const float* __restrict__ bv_,
                                                bf16* __restrict__ Qp, bf16* __restrict__ Kp,
                                                bf16* __restrict__ Vt) {
    __shared__ __align__(16) bf16 smem[128 * 136];
    bf16* As = smem;
    bf16* Bs = smem + 128 * 32;
    int lane = threadIdx.x & 63, wid = threadIdx.x >> 6;
    int li = lane & 15, lg = lane >> 4;
    int bx = blockIdx.x, by = blockIdx.y;
    int which = bx >> 3;
    const bf16* A = which == 0 ? Aq : (which == 1 ? Ak : Av);
    const bf16* W = which == 0 ? Wq_ : (which == 1 ? Wk_ : Wv_);
    const float* bias = which == 0 ? bq_ : (which == 1 ? bk_ : bv_);
    float scale = which == 0 ? 0.125f * LOG2E : 1.0f;

    int am0 = by * 128;
    int bn0 = (bx & 7) * 128;
    int srow = lane >> 2, scol = (lane & 3) * 8;

    f32x4 acc[4][4];
#pragma unroll
    for (int i = 0; i < 4; i++)
#pragma unroll
        for (int j = 0; j < 4; j++) acc[i][j] = (f32x4){0.f, 0.f, 0.f, 0.f};

    for (int k0 = 0; k0 < DIN; k0 += 32) {
#pragma unroll
        for (int t = 0; t < 2; t++) {
            int r = (wid * 2 + t) * 16;
            gld16(A + (long)(am0 + r + srow) * DIN + k0 + scol, &As[r * 32], lane);
            gld16(W + (long)(bn0 + r + srow) * DIN + k0 + scol, &Bs[r * 32], lane);
        }
        __syncthreads();
        bf16x8 af[4], bfr[4];
#pragma unroll
        for (int i = 0; i < 4; i++)
            af[i] = *(const bf16x8*)&As[((wid >> 1) * 64 + i * 16 + li) * 32 + lg * 8];
#pragma unroll
        for (int j = 0; j < 4; j++)
            bfr[j] = *(const bf16x8*)&Bs[((wid & 1) * 64 + j * 16 + li) * 32 + lg * 8];
#pragma unroll
        for (int i = 0; i < 4; i++)
#pragma unroll
            for (int j = 0; j < 4; j++)
                acc[i][j] = __builtin_amdgcn_mfma_f32_16x16x32_bf16(af[i], bfr[j], acc[i][j], 0, 0, 0);
        __syncthreads();
    }

    int bb = am0 >> 11;
    int s0 = am0 & 2047;
    if (which == 2) {
        // V: stage C^T into LDS, then coalesced row writes
#pragma unroll
        for (int i = 0; i < 4; i++)
#pragma unroll
            for (int j = 0; j < 4; j++) {
                int nl = (wid & 1) * 64 + j * 16 + li;
                float bv = bias[bn0 + nl];
#pragma unroll
                for (int r = 0; r < 4; r++) {
                    int ml = (wid >> 1) * 64 + i * 16 + lg * 4 + r;
                    smem[nl * 136 + ml] = (bf16)(acc[i][j][r] + bv);
                }
            }
        __syncthreads();
        int t = threadIdx.x, row = t >> 1, half = t & 1;
        int n = bn0 + row, hh = n >> 6, e = n & 63;
        bf16* dst = Vt + (((long)hh * NB + bb) * D + e) * S + s0 + half * 64;
        const bf16* srcp = &smem[row * 136 + half * 64];
#pragma unroll
        for (int k2 = 0; k2 < 8; k2++)
            *(bf16x8*)(dst + k2 * 8) = *(const bf16x8*)(srcp + k2 * 8);
    } else {
        bf16* outp = which == 0 ? Qp : Kp;
#pragma unroll
        for (int i = 0; i < 4; i++) {
#pragma unroll
            for (int j = 0; j < 4; j++) {
                int n = bn0 + (wid & 1) * 64 + j * 16 + li;
                float bv = bias[n];
                int h = n >> 6, e = n & 63;
#pragma unroll
                for (int r = 0; r < 4; r++) {
                    int m = am0 + (wid >> 1) * 64 + i * 16 + lg * 4 + r;
                    int s = m & 2047;
                    float v = (acc[i][j][r] + bv) * scale;
                    outp[(((long)h * NB + bb) * S + s) * D + e] = (bf16)v;
                }
            }
        }
    }
}

// ---------------- flash attention: 512 blocks x 512 threads, 8 waves x 16 q-rows ----------------
// K/V staged once per block in LDS (double-buffered, XOR-source-swizzled, conflict-free ds_read_b128).
// 2 blocks/CU x 8 waves = 16 waves/CU (~50% occupancy) for latency hiding.
// Qp/Kp: bf16 [hb][S][64] (Q pre-scaled by 0.125*log2e); VT: bf16 [hb][64][S]; cat: bf16 [b][s][h*64+e]
__global__ __launch_bounds__(512) void attn_kernel(const bf16* __restrict__ Qp,
                                                   const bf16* __restrict__ Kp,
                                                   const bf16* __restrict__ VT,
                                                   bf16* __restrict__ cat) {
    __shared__ __align__(16) bf16 Ks[2][64 * 64];   // [kv-row][64 d], rows 128B, XOR-swizzled content
    __shared__ __align__(16) bf16 Vs[2][64 * 64];   // [e][64 s-cols of tile]
    __shared__ __align__(16) bf16 plds[8][16][72];  // per-wave P buffer (16 rows x 64, stride 72)
    int lane = threadIdx.x & 63, wid = threadIdx.x >> 6;  // wid 0..7
    int li = lane & 15, lg = lane >> 4;
    // XCD-aware chunked swizzle: 512 blocks -> 64 contiguous per XCD (4 hb = 2MB KV per L2)
    int bid = blockIdx.x;
    int swz = (bid & 7) * 64 + (bid >> 3);
    int hb = swz >> 4, qb = swz & 15;
    int h = hb >> 1, b = hb & 1;
    int q0 = qb * 128 + wid * 16;

    const bf16* Qb = Qp + (long)hb * S * D;
    const bf16* Kb = Kp + (long)hb * S * D;
    const bf16* Vb = VT + (long)hb * D * S;

    // staging lane map: one gld16 covers 8 rows (1KB). lane l -> row l>>3, physical chunk l&7.
    // source fetches LOGICAL chunk (l&7)^(l>>3) => reader XORs chunk with (row&7). conflict-free b128.
    int srow8 = lane >> 3, lc16 = (lane & 7) ^ srow8;

    // hoist Q fragments (16 rows x 64 e per wave)
    bf16x8 qf[2];
#pragma unroll
    for (int ke = 0; ke < 2; ke++)
        qf[ke] = *(const bf16x8*)(Qb + (q0 + li) * D + ke * 32 + lg * 8);

    f32x4 o[4];
    float mrow[4], lrow[4];
#pragma unroll
    for (int ef = 0; ef < 4; ef++) o[ef] = (f32x4){0.f, 0.f, 0.f, 0.f};
#pragma unroll
    for (int r = 0; r < 4; r++) { mrow[r] = -INFINITY; lrow[r] = 0.f; }

    // prologue: stage tile 0 (wave wid stages rows [wid*8, wid*8+8) of both K and V)
    {
        int rb = wid * 8;
        gld16(Kb + (long)(rb + srow8) * D + lc16 * 8, &Ks[0][rb * 64], lane);
        gld16(Vb + (long)(rb + srow8) * S + 0 + lc16 * 8, &Vs[0][rb * 64], lane);
    }
    __syncthreads();
    int buf = 0;

    for (int t0 = 0; t0 < S; t0 += 64) {
        // ---- issue next-tile staging (hides under compute; barrier at loop end drains) ----
        if (t0 + 64 < S) {
            int rb = wid * 8;
            gld16(Kb + (long)(t0 + 64 + rb + srow8) * D + lc16 * 8, &Ks[buf ^ 1][rb * 64], lane);
            gld16(Vb + (long)(rb + srow8) * S + t0 + 64 + lc16 * 8, &Vs[buf ^ 1][rb * 64], lane);
        }

        // ---- K fragments from LDS (swizzled read) ----
        bf16x8 kf[4][2];
#pragma unroll
        for (int tf = 0; tf < 4; tf++)
#pragma unroll
            for (int ke = 0; ke < 2; ke++)
                kf[tf][ke] = *(const bf16x8*)&Ks[buf][(tf * 16 + li) * 64 + (((ke * 4 + lg) ^ (li & 7)) << 3)];

        f32x4 sf[4];
#pragma unroll
        for (int tf = 0; tf < 4; tf++) sf[tf] = (f32x4){0.f, 0.f, 0.f, 0.f};
        __builtin_amdgcn_s_setprio(1);
#pragma unroll
        for (int tf = 0; tf < 4; tf++)
#pragma unroll
            for (int ke = 0; ke < 2; ke++)
                sf[tf] = __builtin_amdgcn_mfma_f32_16x16x32_bf16(qf[ke], kf[tf][ke], sf[tf], 0, 0, 0);
        __builtin_amdgcn_s_setprio(0);

        // ---- online softmax (rows in (lg,r); cols in li across 16 lanes) ----
        float pm[4];
#pragma unroll
        for (int r = 0; r < 4; r++)
            pm[r] = fmaxf(fmaxf(sf[0][r], sf[1][r]), fmaxf(sf[2][r], sf[3][r]));
#pragma unroll
        for (int mask = 1; mask <= 8; mask <<= 1)
#pragma unroll
            for (int r = 0; r < 4; r++) pm[r] = fmaxf(pm[r], __shfl_xor(pm[r], mask));
        float dm = -INFINITY;
#pragma unroll
        for (int r = 0; r < 4; r++) dm = fmaxf(dm, pm[r] - mrow[r]);

        if (__all(dm <= 11.5f)) {
            // defer-max: keep old running max, no rescale (P bounded by 2^11.5)
            float rs[4] = {0.f, 0.f, 0.f, 0.f};
#pragma unroll
            for (int tf = 0; tf < 4; tf++)
#pragma unroll
                for (int r = 0; r < 4; r++) {
                    float p = exp2_hw(sf[tf][r] - mrow[r]);
                    sf[tf][r] = p;
                    rs[r] += p;
                }
#pragma unroll
            for (int mask = 1; mask <= 8; mask <<= 1)
#pragma unroll
                for (int r = 0; r < 4; r++) rs[r] += __shfl_xor(rs[r], mask);
#pragma unroll
            for (int r = 0; r < 4; r++) lrow[r] += rs[r];
        } else {
            float cr[4];
#pragma unroll
            for (int r = 0; r < 4; r++) {
                float mn = fmaxf(mrow[r], pm[r]);
                cr[r] = exp2_hw(mrow[r] - mn);
                mrow[r] = mn;
            }
            float rs[4] = {0.f, 0.f, 0.f, 0.f};
#pragma unroll
            for (int tf = 0; tf < 4; tf++)
#pragma unroll
                for (int r = 0; r < 4; r++) {
                    float p = exp2_hw(sf[tf][r] - mrow[r]);
                    sf[tf][r] = p;
                    rs[r] += p;
                }
#pragma unroll
            for (int mask = 1; mask <= 8; mask <<= 1)
#pragma unroll
                for (int r = 0; r < 4; r++) rs[r] += __shfl_xor(rs[r], mask);
#pragma unroll
            for (int r = 0; r < 4; r++) lrow[r] = lrow[r] * cr[r] + rs[r];
#pragma unroll
            for (int ef = 0; ef < 4; ef++)
#pragma unroll
                for (int r = 0; r < 4; r++) o[ef][r] *= cr[r];
        }

        // ---- transpose P through per-wave LDS into A-fragment layout ----
#pragma unroll
        for (int tf = 0; tf < 4; tf++)
#pragma unroll
            for (int r = 0; r < 4; r++)
                plds[wid][lg * 4 + r][tf * 16 + li] = (bf16)sf[tf][r];
        asm volatile("s_waitcnt lgkmcnt(0)" ::: "memory");

        // ---- V fragments from LDS (swizzled read) + PV ----
        bf16x8 vf[4][2], pf[2];
#pragma unroll
        for (int ef = 0; ef < 4; ef++)
#pragma unroll
            for (int ks = 0; ks < 2; ks++)
                vf[ef][ks] = *(const bf16x8*)&Vs[buf][(ef * 16 + li) * 64 + (((ks * 4 + lg) ^ (li & 7)) << 3)];
#pragma unroll
        for (int ks = 0; ks < 2; ks++)
            pf[ks] = *(const bf16x8*)&plds[wid][li][ks * 32 + lg * 8];
        __builtin_amdgcn_s_setprio(1);
#pragma unroll
        for (int ef = 0; ef < 4; ef++)
#pragma unroll
            for (int ks = 0; ks < 2; ks++)
                o[ef] = __builtin_amdgcn_mfma_f32_16x16x32_bf16(pf[ks], vf[ef][ks], o[ef], 0, 0, 0);
        __builtin_amdgcn_s_setprio(0);

        __syncthreads();  // drains vmcnt (next-tile staging) + lgkm; all waves done with buf
        buf ^= 1;
    }

    // ---- epilogue: divide by l, write cat[b][s][h*64+e] ----
#pragma unroll
    for (int r = 0; r < 4; r++) {
        float inv = 1.0f / lrow[r];
        int s = q0 + lg * 4 + r;
#pragma unroll
        for (int ef = 0; ef < 4; ef++)
            cat[((long)b * S + s) * (H * D) + h * D + ef * 16 + li] = (bf16)(o[ef][r] * inv);
    }
}

// ---------------- output projection, LDS-staged, tile 128x64, grid (16,32) ----------------
__global__ __launch_bounds__(256) void out_gemm(const bf16* __restrict__ A,
                                                const bf16* __restrict__ WoT,
                                                const float* __restrict__ bo,
                                                float* __restrict__ out) {
    __shared__ bf16 As[128 * 32], Bs[64 * 32];
    int lane = threadIdx.x & 63, wid = threadIdx.x >> 6;
    int li = lane & 15, lg = lane >> 4;
    int am0 = blockIdx.y * 128, bn0 = blockIdx.x * 64;
    int srow = lane >> 2, scol = (lane & 3) * 8;

    f32x4 acc[4][2];
#pragma unroll
    for (int i = 0; i < 4; i++)
#pragma unroll
        for (int j = 0; j < 2; j++) acc[i][j] = (f32x4){0.f, 0.f, 0.f, 0.f};

    for (int k0 = 0; k0 < DIN; k0 += 32) {
#pragma unroll
        for (int t = 0; t < 2; t++) {
            int r = (wid * 2 + t) * 16;
            gld16(A + (long)(am0 + r + srow) * DIN + k0 + scol, &As[r * 32], lane);
        }
        gld16(WoT + (long)(bn0 + wid * 16 + srow) * DIN + k0 + scol, &Bs[wid * 16 * 32], lane);
        __syncthreads();
        bf16x8 af[4], bfr[2];
#pragma unroll
        for (int i = 0; i < 4; i++)
            af[i] = *(const bf16x8*)&As[((wid >> 1) * 64 + i * 16 + li) * 32 + lg * 8];
#pragma unroll
        for (int j = 0; j < 2; j++)
            bfr[j] = *(const bf16x8*)&Bs[((wid & 1) * 32 + j * 16 + li) * 32 + lg * 8];
#pragma unroll
        for (int i = 0; i < 4; i++)
#pragma unroll
            for (int j = 0; j < 2; j++)
                acc[i][j] = __builtin_amdgcn_mfma_f32_16x16x32_bf16(af[i], bfr[j], acc[i][j], 0, 0, 0);
        __syncthreads();
    }

#pragma unroll
    for (int i = 0; i < 4; i++) {
#pragma unroll
        for (int j = 0; j < 2; j++) {
            int n = bn0 + (wid & 1) * 32 + j * 16 + li;
            float bv = bo[n];
#pragma unroll
            for (int r = 0; r < 4; r++) {
                int m = am0 + (wid >> 1) * 64 + i * 16 + lg * 4 + r;
                out[(long)m * DIN + n] = acc[i][j][r] + bv;
            }
        }
    }
}

extern "C" void kernel_launch(void* const* d_in, const int* in_sizes, int n_in,
                              void* d_out, int out_size, void* d_ws, size_t ws_size,
                              hipStream_t stream) {
    const float* query = (const float*)d_in[0];
    const float* key_  = (const float*)d_in[1];
    const float* value = (const float*)d_in[2];
    const float* Wq = (const float*)d_in[3];
    const float* bq = (const float*)d_in[4];
    const float* Wk = (const float*)d_in[5];
    const float* bk = (const float*)d_in[6];
    const float* Wv = (const float*)d_in[7];
    const float* bv = (const float*)d_in[8];
    const float* Wo = (const float*)d_in[9];
    const float* bo = (const float*)d_in[10];
    float* out = (float*)d_out;

    char* w = (char*)d_ws;
    size_t off = 0;
    auto take = [&](size_t bytes) -> char* {
        char* p = w + off;
        off += (bytes + 255) & ~(size_t)255;
        return p;
    };
    bf16* Xbq = (bf16*)take((size_t)BS * DIN * 2);
    bf16* Xbk = (bf16*)take((size_t)BS * DIN * 2);
    bf16* Xbv = (bf16*)take((size_t)BS * DIN * 2);
    bf16* WqT = (bf16*)take((size_t)H * D * DIN * 2);
    bf16* WkT = (bf16*)take((size_t)H * D * DIN * 2);
    bf16* WvT = (bf16*)take((size_t)H * D * DIN * 2);
    bf16* WoT = (bf16*)take((size_t)DIN * (H * D) * 2);
    bf16* Qp  = (bf16*)take((size_t)H * NB * S * D * 2);
    bf16* Kp  = (bf16*)take((size_t)H * NB * S * D * 2);
    bf16* VTs = (bf16*)take((size_t)H * NB * D * S * 2);
    bf16* cat = (bf16*)take((size_t)BS * (H * D) * 2);

    int n4 = BS * DIN / 4;
    cvt3_f32_bf16<<<dim3(n4 / 256, 3), 256, 0, stream>>>(
        (const float4*)query, (const float4*)key_, (const float4*)value,
        (bf16x4*)Xbq, (bf16x4*)Xbk, (bf16x4*)Xbv, n4);

    transpose3_cvt<<<dim3(D / 32, DIN / 32, 3 * H), 256, 0, stream>>>(Wq, Wk, Wv, WqT, WkT, WvT);
    transpose_cvt_sq<<<dim3(DIN / 32, DIN / 32), 256, 0, stream>>>(Wo, WoT, DIN);

    qkv_gemm<<<dim3(24, 32), 256, 0, stream>>>(Xbq, Xbk, Xbv, WqT, WkT, WvT, bq, bk, bv, Qp, Kp, VTs);

    attn_kernel<<<dim3(512), 512, 0, stream>>>(Qp, Kp, VTs, cat);

    out_gemm<<<dim3(16, 32), 256, 0, stream>>>(cat, WoT, bo, out);
}